// Round 4
// baseline (132.204 us; speedup 1.0000x reference)
//
#include <hip/hip_runtime.h>
#include <math.h>

#define NB   4      // n
#define C    128    // channels
#define S    31     // frames
#define HW   704    // h*w = 32*22
#define T    30     // s-1
#define NS   120    // n*(s-1)
#define K    16     // top_k

// ---------------------------------------------------------------------------
// Kernel 1: 1x1 conv (C->1) for both weight vectors, 4-way channel split.
// Block = 256 threads = 64 pixels x 4 channel-groups of 32, LDS combine.
// 1364 blocks (~5.3 waves/SIMD). BW-bound at the 45 MB x-read (~7.2 us).
// ---------------------------------------------------------------------------
__global__ __launch_bounds__(256) void conv_kernel(
    const float* __restrict__ x,
    const float* __restrict__ w1, const float* __restrict__ b1p,
    const float* __restrict__ w2, const float* __restrict__ b2p,
    float* __restrict__ A, float* __restrict__ B) {
  const int tid   = threadIdx.x;
  const int chunk = blockIdx.x % 11;       // 11 chunks of 64 pixels = 704
  const int fr    = blockIdx.x / 11;       // 0..123 = (n, sf)
  const int sf    = fr % S;
  const int n     = fr / S;
  const int p     = chunk * 64 + (tid & 63);
  const int cg    = tid >> 6;              // 0..3

  const float* xp = x + (((size_t)(n * C + cg * 32) * S + sf) * HW) + p;
  const float* wA = w1 + cg * 32;
  const float* wB = w2 + cg * 32;
  float acc1 = 0.f, acc2 = 0.f;
#pragma unroll
  for (int c = 0; c < 32; ++c) {
    float xv = xp[(size_t)c * (S * HW)];
    acc1 = fmaf(xv, wA[c], acc1);
    acc2 = fmaf(xv, wB[c], acc2);
  }
  __shared__ float s1[256], s2[256];
  s1[tid] = acc1;
  s2[tid] = acc2;
  __syncthreads();
  if (tid < 64) {
    float a1 = (s1[tid] + s1[tid + 64]) + (s1[tid + 128] + s1[tid + 192]);
    float a2 = (s2[tid] + s2[tid + 64]) + (s2[tid + 128] + s2[tid + 192]);
    if (sf < T)  A[(n * T + sf) * HW + p]       = a1 + b1p[0];
    if (sf >= 1) B[(n * T + (sf - 1)) * HW + p] = a2 + b2p[0];
  }
}

// ---------------------------------------------------------------------------
// Kernel 2 (fused sort + softmax): one block of 512 threads per frame pair.
// Phase 1: bitonic sort of b_i (padded to 1024 with +INF) in LDS -> top-16
// desc / bottom-16 asc kept in LDS (no global round-trip, one fewer launch).
// Phase 2: 8 waves x 88 rows, 4 rows per iteration for ILP: 11 LDS b-reads
// feed 44 exps, covering the exp/add dependency chain at 2 waves/SIMD.
// b reads come from LDS (lane l -> word l: conflict-free broadcast-free
// stride-1, 2-way aliasing = free), replacing R3's 238 MB of L1/L2 re-reads.
// m = exact row max of a*b so every exponent <= 0; a==0 -> uniform 1/704.
// Output raw-reshape: row r's 16 vals -> (j_out=r/44, p_out=(r%44)*16),
// 16 contiguous floats per row.
// ---------------------------------------------------------------------------
__global__ __launch_bounds__(512) void sort_softmax_kernel(
    const float* __restrict__ A, const float* __restrict__ B,
    float* __restrict__ out) {
  __shared__ float s[1024];
  __shared__ float sB[HW];
  __shared__ float sA[HW];
  __shared__ float stp[K], sbt[K];
  const int i   = blockIdx.x;
  const int tid = threadIdx.x;
  const float* bi = B + i * HW;
  const float* ai = A + i * HW;
  for (int q = tid; q < 1024; q += 512) {
    float v = (q < HW) ? bi[q] : INFINITY;
    s[q] = v;
    if (q < HW) { sB[q] = v; sA[q] = ai[q]; }
  }
  __syncthreads();

  // bitonic sort ascending (55 passes)
#pragma unroll 1
  for (int k = 2; k <= 1024; k <<= 1) {
#pragma unroll 1
    for (int j = k >> 1; j > 0; j >>= 1) {
#pragma unroll
      for (int idx = tid; idx < 1024; idx += 512) {
        int ixj = idx ^ j;
        if (ixj > idx) {
          float a = s[idx], b = s[ixj];
          if ((a > b) == ((idx & k) == 0)) { s[idx] = b; s[ixj] = a; }
        }
      }
      __syncthreads();
    }
  }
  if (tid < K) {
    sbt[tid] = s[tid];            // 16 smallest, ascending
    stp[tid] = s[HW - 1 - tid];   // 16 largest, descending
  }
  __syncthreads();

  const int lane = tid & 63;
  const int wv   = tid >> 6;
  const float L2E = 1.4426950408889634f;
  const float t0  = stp[0], b0 = sbt[0];
  const int   n   = i / T;
  const int   t   = i % T;
  float* obase = out + (((size_t)n * K) * T + t) * HW;

#pragma unroll 1
  for (int g = 0; g < 22; ++g) {
    const int r0 = wv * 88 + g * 4;
    float av[4], a2[4], nm[4], part[4];
#pragma unroll
    for (int u = 0; u < 4; ++u) {
      av[u]   = sA[r0 + u];                       // LDS broadcast
      a2[u]   = av[u] * L2E;
      nm[u]   = -((av[u] >= 0.f) ? av[u] * t0 : av[u] * b0) * L2E;
      part[u] = 0.f;
    }
#pragma unroll
    for (int j = 0; j < 11; ++j) {
      float bv = sB[j * 64 + lane];
#pragma unroll
      for (int u = 0; u < 4; ++u)
        part[u] += __builtin_amdgcn_exp2f(fmaf(a2[u], bv, nm[u]));
    }
#pragma unroll
    for (int off = 1; off < 64; off <<= 1) {
#pragma unroll
      for (int u = 0; u < 4; ++u)
        part[u] += __shfl_xor(part[u], off, 64);
    }
    if (lane < K) {
#pragma unroll
      for (int u = 0; u < 4; ++u) {
        const int r   = r0 + u;
        const float sel = (av[u] >= 0.f) ? stp[lane] : sbt[lane];
        const float val = __builtin_amdgcn_exp2f(fmaf(a2[u], sel, nm[u])) / part[u];
        obase[(size_t)(r / 44) * (T * HW) + (r % 44) * K + lane] = val;
      }
    }
  }
}

extern "C" void kernel_launch(void* const* d_in, const int* in_sizes, int n_in,
                              void* d_out, int out_size, void* d_ws, size_t ws_size,
                              hipStream_t stream) {
  (void)in_sizes; (void)n_in; (void)out_size; (void)ws_size;
  const float* x  = (const float*)d_in[0];
  const float* w1 = (const float*)d_in[1];
  const float* b1 = (const float*)d_in[2];
  const float* w2 = (const float*)d_in[3];
  const float* b2 = (const float*)d_in[4];
  // d_in[5] is top_k (=16), hardcoded as K.
  float* out = (float*)d_out;

  float* A = (float*)d_ws;              // NS*HW
  float* B = A + NS * HW;               // NS*HW

  conv_kernel<<<124 * 11, 256, 0, stream>>>(x, w1, b1, w2, b2, A, B);
  sort_softmax_kernel<<<NS, 512, 0, stream>>>(A, B, out);
}

// Round 5
// 121.604 us; speedup vs baseline: 1.0872x; 1.0872x over previous
//
#include <hip/hip_runtime.h>
#include <math.h>

#define NB   4      // n
#define C    128    // channels
#define S    31     // frames
#define HW   704    // h*w = 32*22
#define T    30     // s-1
#define NS   120    // n*(s-1)
#define K    16     // top_k

// ---------------------------------------------------------------------------
// Kernel 1: 1x1 conv (C->1) for both weight vectors, 4-way channel split.
// Block = 256 threads = 64 pixels x 4 channel-groups of 32, LDS combine.
// 1364 blocks (~5.3 waves/SIMD). BW-bound at the 45 MB x-read (~8 us).
// ---------------------------------------------------------------------------
__global__ __launch_bounds__(256) void conv_kernel(
    const float* __restrict__ x,
    const float* __restrict__ w1, const float* __restrict__ b1p,
    const float* __restrict__ w2, const float* __restrict__ b2p,
    float* __restrict__ A, float* __restrict__ B) {
  const int tid   = threadIdx.x;
  const int chunk = blockIdx.x % 11;       // 11 chunks of 64 pixels = 704
  const int fr    = blockIdx.x / 11;       // 0..123 = (n, sf)
  const int sf    = fr % S;
  const int n     = fr / S;
  const int p     = chunk * 64 + (tid & 63);
  const int cg    = tid >> 6;              // 0..3

  const float* xp = x + (((size_t)(n * C + cg * 32) * S + sf) * HW) + p;
  const float* wA = w1 + cg * 32;
  const float* wB = w2 + cg * 32;
  float acc1 = 0.f, acc2 = 0.f;
#pragma unroll
  for (int c = 0; c < 32; ++c) {
    float xv = xp[(size_t)c * (S * HW)];
    acc1 = fmaf(xv, wA[c], acc1);
    acc2 = fmaf(xv, wB[c], acc2);
  }
  __shared__ float s1[256], s2[256];
  s1[tid] = acc1;
  s2[tid] = acc2;
  __syncthreads();
  if (tid < 64) {
    float a1 = (s1[tid] + s1[tid + 64]) + (s1[tid + 128] + s1[tid + 192]);
    float a2 = (s2[tid] + s2[tid + 64]) + (s2[tid + 128] + s2[tid + 192]);
    if (sf < T)  A[(n * T + sf) * HW + p]       = a1 + b1p[0];
    if (sf >= 1) B[(n * T + (sf - 1)) * HW + p] = a2 + b2p[0];
  }
}

// ---------------------------------------------------------------------------
// Kernel 2: bitonic sort (ascending) of each frame-pair's 704 b-values,
// padded to 1024 with +INF. One block of 512 threads per pair, 55 passes.
// Small kernel (~5 us); the softmax stays SPLIT so it can run at full
// occupancy (R4's fusion collapsed to 0.94 waves/SIMD -> 51.6 us).
// ---------------------------------------------------------------------------
__global__ __launch_bounds__(512) void sort_kernel(
    const float* __restrict__ B,
    float* __restrict__ btop, float* __restrict__ bbot) {
  __shared__ float s[1024];
  const int i   = blockIdx.x;
  const int tid = threadIdx.x;
  const float* bi = B + i * HW;
  for (int q = tid; q < 1024; q += 512)
    s[q] = (q < HW) ? bi[q] : INFINITY;
  __syncthreads();
#pragma unroll 1
  for (int k = 2; k <= 1024; k <<= 1) {
#pragma unroll 1
    for (int j = k >> 1; j > 0; j >>= 1) {
#pragma unroll
      for (int idx = tid; idx < 1024; idx += 512) {
        int ixj = idx ^ j;
        if (ixj > idx) {
          float a = s[idx], b = s[ixj];
          if ((a > b) == ((idx & k) == 0)) { s[idx] = b; s[ixj] = a; }
        }
      }
      __syncthreads();
    }
  }
  if (tid < K) {
    bbot[i * K + tid] = s[tid];            // 16 smallest, ascending
    btop[i * K + tid] = s[HW - 1 - tid];   // 16 largest, descending
  }
}

// ---------------------------------------------------------------------------
// Kernel 3: one wave per TWO rows of the same frame pair (r, r+352).
// 42240 waves (~8 blocks/CU TLP). Each b element loaded once feeds 2 exps
// (halves L2 re-read to ~119 MB, 2-way ILP on the exp chain, half the
// butterfly reductions). Lane l covers q = j*64+l (coalesced). ln2 folded
// into the fma -> raw v_exp_f32 via exp2. m = exact row max of a*b so every
// exponent <= 0; a==0 degenerates to uniform 1/704. Output raw-reshape:
// row r -> (j_out=r/44, p_out=(r%44)*16), 16 contiguous floats.
// ---------------------------------------------------------------------------
__global__ __launch_bounds__(256) void softmax_topk_kernel(
    const float* __restrict__ A, const float* __restrict__ B,
    const float* __restrict__ btop, const float* __restrict__ bbot,
    float* __restrict__ out) {
  const int lane = threadIdx.x & 63;
  const int wid  = blockIdx.x * 4 + (threadIdx.x >> 6);  // 0..42239
  const int i    = wid / 352;                            // frame pair
  const int r0   = wid % 352;
  const int r1   = r0 + 352;

  const float st0 = btop[i * K];
  const float sb0 = bbot[i * K];
  const float av0 = A[i * HW + r0];
  const float av1 = A[i * HW + r1];
  const float L2E = 1.4426950408889634f;
  const float a20 = av0 * L2E;
  const float a21 = av1 * L2E;
  const float nm0 = -((av0 >= 0.f) ? av0 * st0 : av0 * sb0) * L2E;
  const float nm1 = -((av1 >= 0.f) ? av1 * st0 : av1 * sb0) * L2E;

  const float* __restrict__ bi = B + i * HW;
  float p0 = 0.f, p1 = 0.f;
#pragma unroll
  for (int j = 0; j < 11; ++j) {
    float bv = bi[j * 64 + lane];
    p0 += __builtin_amdgcn_exp2f(fmaf(a20, bv, nm0));
    p1 += __builtin_amdgcn_exp2f(fmaf(a21, bv, nm1));
  }
#pragma unroll
  for (int off = 1; off < 64; off <<= 1) {
    p0 += __shfl_xor(p0, off, 64);
    p1 += __shfl_xor(p1, off, 64);
  }

  if (lane < K) {
    const int n  = i / T;
    const int t  = i % T;
    float* obase = out + (((size_t)n * K) * T + t) * HW;
    const float sel0 = (av0 >= 0.f) ? btop[i * K + lane] : bbot[i * K + lane];
    const float sel1 = (av1 >= 0.f) ? btop[i * K + lane] : bbot[i * K + lane];
    const float v0 = __builtin_amdgcn_exp2f(fmaf(a20, sel0, nm0)) / p0;
    const float v1 = __builtin_amdgcn_exp2f(fmaf(a21, sel1, nm1)) / p1;
    obase[(size_t)(r0 / 44) * (T * HW) + (r0 % 44) * K + lane] = v0;
    obase[(size_t)(r1 / 44) * (T * HW) + (r1 % 44) * K + lane] = v1;
  }
}

extern "C" void kernel_launch(void* const* d_in, const int* in_sizes, int n_in,
                              void* d_out, int out_size, void* d_ws, size_t ws_size,
                              hipStream_t stream) {
  (void)in_sizes; (void)n_in; (void)out_size; (void)ws_size;
  const float* x  = (const float*)d_in[0];
  const float* w1 = (const float*)d_in[1];
  const float* b1 = (const float*)d_in[2];
  const float* w2 = (const float*)d_in[3];
  const float* b2 = (const float*)d_in[4];
  // d_in[5] is top_k (=16), hardcoded as K.
  float* out = (float*)d_out;

  float* A    = (float*)d_ws;            // NS*HW
  float* B    = A + NS * HW;             // NS*HW
  float* btop = B + NS * HW;             // NS*K
  float* bbot = btop + NS * K;           // NS*K

  conv_kernel<<<124 * 11, 256, 0, stream>>>(x, w1, b1, w2, b2, A, B);
  sort_kernel<<<NS, 512, 0, stream>>>(B, btop, bbot);
  // 42240 waves / 4 waves-per-block = 10560 blocks
  softmax_topk_kernel<<<10560, 256, 0, stream>>>(A, B, btop, bbot, out);
}

// Round 6
// 118.101 us; speedup vs baseline: 1.1194x; 1.0297x over previous
//
#include <hip/hip_runtime.h>
#include <math.h>

#define NB   4      // n
#define C    128    // channels
#define S    31     // frames
#define HW   704    // h*w = 32*22
#define T    30     // s-1
#define NS   120    // n*(s-1)
#define K    16     // top_k

// ---------------------------------------------------------------------------
// Kernel 1: 1x1 conv (C->1), float4-vectorized. Each lane owns one float4
// (4 consecutive pixels); wave = 256 contiguous pixels; 4 waves/block = 4
// channel-groups of 32, LDS combine. 341 blocks x 4 waves = 1364 waves
// (~5.3/SIMD). 16B/lane loads (global_load_dwordx4) -> BW floor ~7.2 us.
// ---------------------------------------------------------------------------
__global__ __launch_bounds__(256) void conv_kernel(
    const float* __restrict__ x,
    const float* __restrict__ w1, const float* __restrict__ b1p,
    const float* __restrict__ w2, const float* __restrict__ b2p,
    float* __restrict__ A, float* __restrict__ B) {
  const int tid  = threadIdx.x;
  const int lane = tid & 63;
  const int cg   = tid >> 6;                 // wave-uniform channel group
  const int g    = blockIdx.x * 64 + lane;   // float4 index, 0..21823
  const int fr   = g / 176;                  // (n, sf), 176 float4s per frame
  const int f4   = g % 176;
  const int sf   = fr % S;
  const int n    = fr / S;

  const float4* xp =
      (const float4*)(x + (((size_t)(n * C + cg * 32) * S + sf) * HW)) + f4;
  float4 a1 = make_float4(0.f, 0.f, 0.f, 0.f);
  float4 a2 = make_float4(0.f, 0.f, 0.f, 0.f);
#pragma unroll
  for (int c = 0; c < 32; ++c) {
    float4 xv = xp[(size_t)c * (S * HW / 4)];
    const float wa = w1[cg * 32 + c];        // wave-uniform -> s_load
    const float wb = w2[cg * 32 + c];
    a1.x = fmaf(xv.x, wa, a1.x); a1.y = fmaf(xv.y, wa, a1.y);
    a1.z = fmaf(xv.z, wa, a1.z); a1.w = fmaf(xv.w, wa, a1.w);
    a2.x = fmaf(xv.x, wb, a2.x); a2.y = fmaf(xv.y, wb, a2.y);
    a2.z = fmaf(xv.z, wb, a2.z); a2.w = fmaf(xv.w, wb, a2.w);
  }
  __shared__ float4 s1[4][64];
  __shared__ float4 s2[4][64];
  s1[cg][lane] = a1;
  s2[cg][lane] = a2;
  __syncthreads();
  if (tid < 64) {
    float4 r1 = s1[0][tid], r2 = s2[0][tid];
#pragma unroll
    for (int u = 1; u < 4; ++u) {
      float4 t1 = s1[u][tid], t2 = s2[u][tid];
      r1.x += t1.x; r1.y += t1.y; r1.z += t1.z; r1.w += t1.w;
      r2.x += t2.x; r2.y += t2.y; r2.z += t2.z; r2.w += t2.w;
    }
    const float bb1 = b1p[0], bb2 = b2p[0];
    r1.x += bb1; r1.y += bb1; r1.z += bb1; r1.w += bb1;
    r2.x += bb2; r2.y += bb2; r2.z += bb2; r2.w += bb2;
    if (sf < T)
      ((float4*)(A + (size_t)(n * T + sf) * HW))[f4] = r1;
    if (sf >= 1)
      ((float4*)(B + (size_t)(n * T + sf - 1) * HW))[f4] = r2;
  }
}

// ---------------------------------------------------------------------------
// Kernel 2: bitonic sort (ascending) of each frame-pair's 704 b-values,
// padded to 1024 with +INF. One block of 512 threads per pair, 55 passes.
// bottom-16 asc = s[0..15]; top-16 desc = s[703], s[702], ...
// ---------------------------------------------------------------------------
__global__ __launch_bounds__(512) void sort_kernel(
    const float* __restrict__ B,
    float* __restrict__ btop, float* __restrict__ bbot) {
  __shared__ float s[1024];
  const int i   = blockIdx.x;
  const int tid = threadIdx.x;
  const float* bi = B + i * HW;
  for (int q = tid; q < 1024; q += 512)
    s[q] = (q < HW) ? bi[q] : INFINITY;
  __syncthreads();
#pragma unroll 1
  for (int k = 2; k <= 1024; k <<= 1) {
#pragma unroll 1
    for (int j = k >> 1; j > 0; j >>= 1) {
#pragma unroll
      for (int idx = tid; idx < 1024; idx += 512) {
        int ixj = idx ^ j;
        if (ixj > idx) {
          float a = s[idx], b = s[ixj];
          if ((a > b) == ((idx & k) == 0)) { s[idx] = b; s[ixj] = a; }
        }
      }
      __syncthreads();
    }
  }
  if (tid < K) {
    bbot[i * K + tid] = s[tid];            // 16 smallest, ascending
    btop[i * K + tid] = s[HW - 1 - tid];   // 16 largest, descending
  }
}

// ---------------------------------------------------------------------------
// Kernel 3: one wave per FOUR rows of the same frame pair (r, r+176, r+352,
// r+528). 21120 waves, 5280 blocks (~20 waves/CU TLP). Each b element
// loaded once feeds 4 exps (L2 re-read quartered to ~60 MB, 4-way ILP on
// the exp chain, quarter the butterfly work). Lane l covers q = j*64+l
// (coalesced). ln2 folded into the fma -> raw v_exp_f32. m = exact row max
// of a*b so every exponent <= 0; a==0 -> uniform 1/704 automatically.
// Output raw-reshape: row r -> (j_out=r/44, p_out=(r%44)*16), 16 contiguous
// floats per row.
// ---------------------------------------------------------------------------
__global__ __launch_bounds__(256) void softmax_topk_kernel(
    const float* __restrict__ A, const float* __restrict__ B,
    const float* __restrict__ btop, const float* __restrict__ bbot,
    float* __restrict__ out) {
  const int lane = threadIdx.x & 63;
  const int wid  = blockIdx.x * 4 + (threadIdx.x >> 6);  // 0..21119
  const int i    = wid / 176;                            // frame pair
  const int rb   = wid % 176;                            // base row

  const float st0 = btop[i * K];
  const float sb0 = bbot[i * K];
  const float L2E = 1.4426950408889634f;
  float av[4], a2[4], nm[4], part[4];
#pragma unroll
  for (int u = 0; u < 4; ++u) {
    av[u]   = A[i * HW + rb + u * 176];
    a2[u]   = av[u] * L2E;
    nm[u]   = -((av[u] >= 0.f) ? av[u] * st0 : av[u] * sb0) * L2E;
    part[u] = 0.f;
  }

  const float* __restrict__ bi = B + i * HW;
#pragma unroll
  for (int j = 0; j < 11; ++j) {
    const float bv = bi[j * 64 + lane];
#pragma unroll
    for (int u = 0; u < 4; ++u)
      part[u] += __builtin_amdgcn_exp2f(fmaf(a2[u], bv, nm[u]));
  }
#pragma unroll
  for (int off = 1; off < 64; off <<= 1) {
#pragma unroll
    for (int u = 0; u < 4; ++u)
      part[u] += __shfl_xor(part[u], off, 64);
  }

  if (lane < K) {
    const int n  = i / T;
    const int t  = i % T;
    float* obase = out + (((size_t)n * K) * T + t) * HW;
    const float tv = btop[i * K + lane];
    const float bv = bbot[i * K + lane];
#pragma unroll
    for (int u = 0; u < 4; ++u) {
      const int r = rb + u * 176;
      const float sel = (av[u] >= 0.f) ? tv : bv;
      const float val = __builtin_amdgcn_exp2f(fmaf(a2[u], sel, nm[u])) / part[u];
      obase[(size_t)(r / 44) * (T * HW) + (r % 44) * K + lane] = val;
    }
  }
}

extern "C" void kernel_launch(void* const* d_in, const int* in_sizes, int n_in,
                              void* d_out, int out_size, void* d_ws, size_t ws_size,
                              hipStream_t stream) {
  (void)in_sizes; (void)n_in; (void)out_size; (void)ws_size;
  const float* x  = (const float*)d_in[0];
  const float* w1 = (const float*)d_in[1];
  const float* b1 = (const float*)d_in[2];
  const float* w2 = (const float*)d_in[3];
  const float* b2 = (const float*)d_in[4];
  // d_in[5] is top_k (=16), hardcoded as K.
  float* out = (float*)d_out;

  float* A    = (float*)d_ws;            // NS*HW
  float* B    = A + NS * HW;             // NS*HW
  float* btop = B + NS * HW;             // NS*K
  float* bbot = btop + NS * K;           // NS*K

  conv_kernel<<<341, 256, 0, stream>>>(x, w1, b1, w2, b2, A, B);
  sort_kernel<<<NS, 512, 0, stream>>>(B, btop, bbot);
  // 21120 waves / 4 waves-per-block = 5280 blocks
  softmax_topk_kernel<<<5280, 256, 0, stream>>>(A, B, btop, bbot, out);
}